// Round 3
// baseline (23290.974 us; speedup 1.0000x reference)
//
#include <hip/hip_runtime.h>
#include <cstdint>
#include <cstddef>

// ---------------------------------------------------------------------------
// AttentionWordRNN on MI355X — ROUND 3: fused MFMA biLSTM scan (no xp tensor).
// ws_size is 256 MiB (learned via sentinel) -> x_proj folded into the scan as
// K-concat [x(384) | h(512)] per step; weights live in VGPRs (28 A-frags),
// B staged fragment-linear in LDS; 32-wg barrier groups; c-state in registers.
// Footprint: 93 MB. Scan bf16 MFMA/fp32 accum; W_word stays fp32 this round.
// ---------------------------------------------------------------------------

#define T_    512
#define B_    64
#define E_    256
#define CD_   128
#define EC_   384      // E + CDIM
#define H_    512
#define NCLS  5
#define NTOK  32768    // T*B

// byte offsets into d_ws
#define OFF_X      0UL
#define OFF_HSC    25165824UL
#define OFF_LOG    92274688UL
#define OFF_ATTN   92405760UL
#define OFF_CTX    92536832UL
#define OFF_CNT    92798976UL
#define WS_REQ     92803072UL

typedef __attribute__((ext_vector_type(8))) short bf16x8;
typedef __attribute__((ext_vector_type(4))) float f32x4;

__device__ __forceinline__ unsigned short f2bf(float f) {
  union { float f; unsigned u; } v; v.f = f;
  unsigned r = v.u + 0x7FFFu + ((v.u >> 16) & 1u);   // RNE
  return (unsigned short)(r >> 16);
}
__device__ __forceinline__ float bf2f(unsigned short h) {
  union { unsigned u; float f; } v; v.u = ((unsigned)h) << 16;
  return v.f;
}

// ---------------- ws-too-small sentinel ----------------
__global__ void k_sentinel(float* __restrict__ out, int n, float val) {
  int i = blockIdx.x * 64 + threadIdx.x;
  if (i < n) out[i] = val;
}

// ---------------- gather + concat -> x bf16 [NTOK][384] ----------------
__global__ __launch_bounds__(256) void k_gather(
    const int* __restrict__ embed, const float* __restrict__ c_embed,
    const float* __restrict__ etab, unsigned short* __restrict__ x) {
  int idx = blockIdx.x * 256 + threadIdx.x;     // NTOK*48 exact
  int n = idx / 48;
  int q8 = idx - n * 48;
  float f[8];
  if (q8 < 32) {
    int tok = embed[n];
    const float* src = etab + (size_t)tok * E_ + q8 * 8;
#pragma unroll
    for (int j = 0; j < 8; ++j) f[j] = src[j];
  } else {
    const float* src = c_embed + (size_t)n * CD_ + (q8 - 32) * 8;
#pragma unroll
    for (int j = 0; j < 8; ++j) f[j] = src[j];
  }
  union { uint4 v; unsigned short s[8]; } u;
#pragma unroll
  for (int j = 0; j < 8; ++j) u.s[j] = f2bf(f[j]);
  *(uint4*)(x + (size_t)n * EC_ + q8 * 8) = u.v;
}

// ---------------- fused biLSTM scan: x_proj + recurrence, MFMA ----------------
// 256 wgs = dir(2) x batch-group(4, 16 batch) x unit-group(32, 16 units).
// 4 waves/wg; wave owns 16 gate-rows (4 units x 4 gates, row = u*4+g).
// A (weights, K=384 x-part + 512 h-part) in VGPRs; B staged frag-linear in LDS.
__global__ __launch_bounds__(256) void k_scan(
    const unsigned short* __restrict__ x,
    const float* __restrict__ wih_f, const float* __restrict__ whh_f,
    const float* __restrict__ wih_b, const float* __restrict__ whh_b,
    const float* __restrict__ bias_f, const float* __restrict__ bias_b,
    const float* __restrict__ h0, const float* __restrict__ c0,
    unsigned short* __restrict__ Hsc,            // [T][B][1024] bf16
    int* __restrict__ cnt) {
  __shared__ uint4 Bs[1792];                     // 28 ktiles x 64 lanes x 16B
  const int tid  = threadIdx.x;
  const int lane = tid & 63;
  const int w    = tid >> 6;                     // wave 0..3
  const int gid  = blockIdx.x;
  const int dir  = gid >> 7;
  const int bg   = (gid >> 5) & 3;
  const int ug   = gid & 31;
  const int grp  = dir * 4 + bg;

  const float* wih  = dir ? wih_b  : wih_f;      // [2048][384]
  const float* whh  = dir ? whh_b  : whh_f;      // [2048][512]
  const float* bias = dir ? bias_b : bias_f;     // [2048]

  // ---- preload A fragments (bf16) into registers ----
  bf16x8 afrag[28];
  {
    const int m = lane & 15, koct = lane >> 4;   // A-role: row, k-octet
    const int grow = (m & 3) * H_ + ug * 16 + w * 4 + (m >> 2);
#pragma unroll
    for (int kt = 0; kt < 12; ++kt) {
      const float* src = wih + (size_t)grow * EC_ + kt * 32 + koct * 8;
      union { bf16x8 v; unsigned short s[8]; } u;
#pragma unroll
      for (int j = 0; j < 8; ++j) u.s[j] = f2bf(src[j]);
      afrag[kt] = u.v;
    }
#pragma unroll
    for (int kt = 0; kt < 16; ++kt) {
      const float* src = whh + (size_t)grow * H_ + kt * 32 + koct * 8;
      union { bf16x8 v; unsigned short s[8]; } u;
#pragma unroll
      for (int j = 0; j < 8; ++j) u.s[j] = f2bf(src[j]);
      afrag[12 + kt] = u.v;
    }
  }

  // ---- D-role lane identity: (unit, batch); c-state in register ----
  const int bD = bg * 16 + (lane & 15);
  const int jD = ug * 16 + w * 4 + (lane >> 4);
  float bsv[4];
#pragma unroll
  for (int q = 0; q < 4; ++q) bsv[q] = bias[q * H_ + jD];
  float c = c0[(size_t)dir * B_ * H_ + (size_t)bD * H_ + jD];

  const int sb  = tid & 15;                      // staging: batch row
  const int sk8 = tid >> 4;                      // staging: k-octet 0..15

  for (int s = 0; s < T_; ++s) {
    const int cur = dir ? (T_ - 1 - s) : s;
    __syncthreads();
    // stage x part (ktiles 0..11)
#pragma unroll
    for (int p = 0; p < 3; ++p) {
      int k = p * 128 + sk8 * 8;
      uint4 v = *(const uint4*)(x + (size_t)(cur * B_ + bg * 16 + sb) * EC_ + k);
      Bs[(k >> 5) * 64 + ((k >> 3) & 3) * 16 + sb] = v;
    }
    // stage h part (ktiles 12..27)
    if (s == 0) {
      const float* hsrc = h0 + (size_t)dir * B_ * H_ + (size_t)(bg * 16 + sb) * H_;
#pragma unroll
      for (int p = 0; p < 4; ++p) {
        int kh = p * 128 + sk8 * 8;
        union { uint4 v; unsigned short us[8]; } u;
#pragma unroll
        for (int j = 0; j < 8; ++j) u.us[j] = f2bf(hsrc[kh + j]);
        int k = EC_ + kh;
        Bs[(k >> 5) * 64 + ((k >> 3) & 3) * 16 + sb] = u.v;
      }
    } else {
      const int prev = dir ? (cur + 1) : (cur - 1);
      const unsigned short* hsrc = Hsc + (size_t)prev * B_ * 1024
                                   + (size_t)(bg * 16 + sb) * 1024 + dir * H_;
#pragma unroll
      for (int p = 0; p < 4; ++p) {
        int kh = p * 128 + sk8 * 8;
        uint4 v = *(const uint4*)(hsrc + kh);
        int k = EC_ + kh;
        Bs[(k >> 5) * 64 + ((k >> 3) & 3) * 16 + sb] = v;
      }
    }
    __syncthreads();

    f32x4 acc = {0.f, 0.f, 0.f, 0.f};
#pragma unroll
    for (int kt = 0; kt < 28; ++kt) {
      bf16x8 bfrag = ((const bf16x8*)Bs)[kt * 64 + lane];
      acc = __builtin_amdgcn_mfma_f32_16x16x32_bf16(afrag[kt], bfrag, acc, 0, 0, 0);
    }

    float gi = acc[0] + bsv[0];
    float gf = acc[1] + bsv[1];
    float gg = acc[2] + bsv[2];
    float go = acc[3] + bsv[3];
    float si = 1.f / (1.f + __expf(-gi));
    float sf = 1.f / (1.f + __expf(-gf));
    float so = 1.f / (1.f + __expf(-go));
    c = sf * c + si * tanhf(gg);
    float h = so * tanhf(c);
    Hsc[(size_t)cur * B_ * 1024 + (size_t)bD * 1024 + dir * H_ + jD] = f2bf(h);

    if (s + 1 < T_) {
      __threadfence();                           // release h stores (agent)
      __syncthreads();
      if (tid == 0) {
        int* p = cnt + grp * 16;
        __hip_atomic_fetch_add(p, 1, __ATOMIC_RELEASE, __HIP_MEMORY_SCOPE_AGENT);
        const int target = 32 * (s + 1);         // monotonic counter
        while (__hip_atomic_load(p, __ATOMIC_RELAXED, __HIP_MEMORY_SCOPE_AGENT)
               < target)
          __builtin_amdgcn_s_sleep(2);
      }
      __syncthreads();
      __threadfence();                           // acquire: invalidate caches
    }
  }
}

// ---------------- W_word GEMM fused tanh * w_proj -> logits (fp32) ---------
__global__ __launch_bounds__(256) void k_wword(
    const unsigned short* __restrict__ Hsc, const float* __restrict__ Ww,
    const float* __restrict__ bw, const float* __restrict__ wp,
    float* __restrict__ logits) {
  __shared__ float As[16][132];
  __shared__ float Bsm[16][132];
  __shared__ float scratch[128][17];
  const int tid = threadIdx.x;
  const int db = blockIdx.x, nb = blockIdx.y;
  const int tg = tid >> 4, tn = tid & 15;
  float acc[8][8];
#pragma unroll
  for (int i = 0; i < 8; ++i)
#pragma unroll
    for (int j = 0; j < 8; ++j) acc[i][j] = 0.f;

  for (int k0 = 0; k0 < 1024; k0 += 16) {
    __syncthreads();
    {                                            // A: Hout bf16, 128r x 16k
      int r = tid >> 1, ko = tid & 1;
      union { uint4 v; unsigned short s[8]; } u;
      u.v = *(const uint4*)(Hsc + (size_t)(nb * 128 + r) * 1024 + k0 + ko * 8);
#pragma unroll
      for (int q = 0; q < 8; ++q) As[ko * 8 + q][r] = bf2f(u.s[q]);
    }
    {                                            // B: W_word fp32, 16k x 128c
      int kk = tid >> 4, cc = (tid & 15) * 8;
      const float* src = Ww + (size_t)(k0 + kk) * 1024 + db * 128 + cc;
      *(float4*)&Bsm[kk][cc]     = *(const float4*)(src);
      *(float4*)&Bsm[kk][cc + 4] = *(const float4*)(src + 4);
    }
    __syncthreads();
#pragma unroll 4
    for (int kk = 0; kk < 16; ++kk) {
      float a[8], b[8];
      *(float4*)&a[0] = *(const float4*)&As[kk][tg * 8];
      *(float4*)&a[4] = *(const float4*)&As[kk][tg * 8 + 4];
      *(float4*)&b[0] = *(const float4*)&Bsm[kk][tn * 4];
      *(float4*)&b[4] = *(const float4*)&Bsm[kk][64 + tn * 4];
#pragma unroll
      for (int rr = 0; rr < 8; ++rr)
#pragma unroll
        for (int cc = 0; cc < 8; ++cc)
          acc[rr][cc] = fmaf(a[rr], b[cc], acc[rr][cc]);
    }
  }
  float bwv[8], wpv[8];
#pragma unroll
  for (int cc = 0; cc < 8; ++cc) {
    int dd = db * 128 + ((cc >= 4) ? 64 : 0) + tn * 4 + (cc & 3);
    bwv[cc] = bw[dd]; wpv[cc] = wp[dd];
  }
  float rs[8];
#pragma unroll
  for (int rr = 0; rr < 8; ++rr) {
    float sum = 0.f;
#pragma unroll
    for (int cc = 0; cc < 8; ++cc)
      sum += tanhf(acc[rr][cc] + bwv[cc]) * wpv[cc];
    rs[rr] = sum;
  }
#pragma unroll
  for (int rr = 0; rr < 8; ++rr) scratch[tg * 8 + rr][tn] = rs[rr];
  __syncthreads();
  if (tid < 128) {
    float sum = 0.f;
#pragma unroll
    for (int j = 0; j < 16; ++j) sum += scratch[tid][j];
    atomicAdd(&logits[nb * 128 + tid], sum);
  }
}

// ---------------- softmax over time (per batch column) ----------------
__global__ __launch_bounds__(256) void k_softmax(
    const float* __restrict__ logits, float* __restrict__ attn) {
  __shared__ float red[256];
  const int b = blockIdx.x, tid = threadIdx.x;
  float v0 = logits[(size_t)tid * B_ + b];
  float v1 = logits[(size_t)(tid + 256) * B_ + b];
  red[tid] = fmaxf(v0, v1);
  __syncthreads();
  for (int off = 128; off; off >>= 1) {
    if (tid < off) red[tid] = fmaxf(red[tid], red[tid + off]);
    __syncthreads();
  }
  float m = red[0];
  __syncthreads();
  float e0 = __expf(v0 - m), e1 = __expf(v1 - m);
  red[tid] = e0 + e1;
  __syncthreads();
  for (int off = 128; off; off >>= 1) {
    if (tid < off) red[tid] += red[tid + off];
    __syncthreads();
  }
  float inv = 1.f / red[0];
  attn[(size_t)tid * B_ + b] = e0 * inv;
  attn[(size_t)(tid + 256) * B_ + b] = e1 * inv;
}

// ---------------- ctx[b][d] = sum_t attn[t,b] * Hout[t,b,d] ----------------
__global__ __launch_bounds__(256) void k_ctx(
    const float* __restrict__ attn, const unsigned short* __restrict__ Hsc,
    float* __restrict__ ctx) {
  __shared__ float al[512];
  const int b = blockIdx.x, dc = blockIdx.y, tid = threadIdx.x;
  al[tid]       = attn[(size_t)tid * B_ + b];
  al[tid + 256] = attn[(size_t)(tid + 256) * B_ + b];
  __syncthreads();
  float acc = 0.f;
  const unsigned short* hp = Hsc + (size_t)b * 1024 + dc * 256 + tid;
#pragma unroll 8
  for (int t = 0; t < T_; ++t)
    acc = fmaf(al[t], bf2f(hp[(size_t)t * B_ * 1024]), acc);
  ctx[b * 1024 + dc * 256 + tid] = acc;
}

// ---------------- final linear: out[b][c] ----------------
__global__ __launch_bounds__(64) void k_out(
    const float* __restrict__ ctx, const float* __restrict__ linW,
    const float* __restrict__ linb, float* __restrict__ out) {
  const int b = blockIdx.x, lane = threadIdx.x;
#pragma unroll
  for (int cc = 0; cc < NCLS; ++cc) {
    float p = 0.f;
    for (int d = lane; d < 1024; d += 64)
      p = fmaf(ctx[b * 1024 + d], linW[cc * 1024 + d], p);
    for (int off = 32; off; off >>= 1) p += __shfl_down(p, off);
    if (lane == 0) out[b * NCLS + cc] = p + linb[cc];
  }
}

// ---------------------------------------------------------------------------
extern "C" void kernel_launch(void* const* d_in, const int* in_sizes, int n_in,
                              void* d_out, int out_size, void* d_ws, size_t ws_size,
                              hipStream_t stream) {
  float* out = (float*)d_out;
  if (ws_size < WS_REQ) {
    k_sentinel<<<(out_size + 63) / 64, 64, 0, stream>>>(
        out, out_size, (float)(ws_size >> 20));
    return;
  }
  const int*   embed   = (const int*)d_in[0];
  const float* c_embed = (const float*)d_in[1];
  const float* h0      = (const float*)d_in[2];
  const float* c0      = (const float*)d_in[3];
  const float* etab    = (const float*)d_in[4];
  const float* w_ih_f  = (const float*)d_in[5];
  const float* w_hh_f  = (const float*)d_in[6];
  const float* b_f     = (const float*)d_in[7];
  const float* w_ih_b  = (const float*)d_in[8];
  const float* w_hh_b  = (const float*)d_in[9];
  const float* b_b     = (const float*)d_in[10];
  const float* W_word  = (const float*)d_in[11];
  const float* b_word  = (const float*)d_in[12];
  const float* w_proj  = (const float*)d_in[13];
  const float* lin_W   = (const float*)d_in[14];
  const float* lin_b   = (const float*)d_in[15];

  char* W = (char*)d_ws;
  unsigned short* x    = (unsigned short*)(W + OFF_X);
  unsigned short* Hsc  = (unsigned short*)(W + OFF_HSC);
  float*  logits = (float*)(W + OFF_LOG);
  float*  attn   = (float*)(W + OFF_ATTN);
  float*  ctx    = (float*)(W + OFF_CTX);
  int*    cnt    = (int*)(W + OFF_CNT);

  // zero logits (atomic target) + barrier counters each launch (replay-safe)
  hipMemsetAsync(logits, 0, 528384, stream);

  k_gather <<<6144, 256, 0, stream>>>(embed, c_embed, etab, x);
  k_scan   <<<256, 256, 0, stream>>>(x, w_ih_f, w_hh_f, w_ih_b, w_hh_b,
                                     b_f, b_b, h0, c0, Hsc, cnt);
  k_wword  <<<dim3(8, 256), 256, 0, stream>>>(Hsc, W_word, b_word, w_proj, logits);
  k_softmax<<<64, 256, 0, stream>>>(logits, attn);
  k_ctx    <<<dim3(64, 4), 256, 0, stream>>>(attn, Hsc, ctx);
  k_out    <<<64, 64, 0, stream>>>(ctx, lin_W, lin_b, out);
}

// Round 4
// 3904.599 us; speedup vs baseline: 5.9650x; 5.9650x over previous
//
#include <hip/hip_runtime.h>
#include <cstdint>
#include <cstddef>

// ---------------------------------------------------------------------------
// AttentionWordRNN on MI355X — ROUND 4: fence-free scan barrier.
// Round-3 post-mortem: 2x __threadfence()/step = L2 wbl2+inv per step -> 44us/
// step, MfmaUtil 0.4%. Fix: h exchanged via sc0/sc1 (agent-relaxed-atomic)
// loads/stores to a 256KB hx buffer; barrier = waitcnt+syncthreads+relaxed
// fetch_add+spin. No cache-maintenance instructions in the loop.
// Scan math/D-mapping/W_word identical to the PASSING round-3 kernel.
// ---------------------------------------------------------------------------

#define T_    512
#define B_    64
#define E_    256
#define CD_   128
#define EC_   384      // E + CDIM
#define H_    512
#define NCLS  5
#define NTOK  32768    // T*B

// byte offsets into d_ws
#define OFF_X      0UL
#define OFF_HSC    25165824UL
#define OFF_LOG    92274688UL
#define OFF_ATTN   92405760UL
#define OFF_CTX    92536832UL
#define OFF_CNT    92798976UL
#define OFF_HX     92803072UL
#define WS_REQ     93065216UL

typedef __attribute__((ext_vector_type(8))) short bf16x8;
typedef __attribute__((ext_vector_type(4))) float f32x4;

__device__ __forceinline__ unsigned short f2bf(float f) {
  union { float f; unsigned u; } v; v.f = f;
  unsigned r = v.u + 0x7FFFu + ((v.u >> 16) & 1u);   // RNE
  return (unsigned short)(r >> 16);
}
__device__ __forceinline__ float bf2f(unsigned short h) {
  union { unsigned u; float f; } v; v.u = ((unsigned)h) << 16;
  return v.f;
}

// ---------------- ws-too-small sentinel ----------------
__global__ void k_sentinel(float* __restrict__ out, int n, float val) {
  int i = blockIdx.x * 64 + threadIdx.x;
  if (i < n) out[i] = val;
}

// ---------------- gather + concat -> x bf16 [NTOK][384] ----------------
__global__ __launch_bounds__(256) void k_gather(
    const int* __restrict__ embed, const float* __restrict__ c_embed,
    const float* __restrict__ etab, unsigned short* __restrict__ x) {
  int idx = blockIdx.x * 256 + threadIdx.x;     // NTOK*48 exact
  int n = idx / 48;
  int q8 = idx - n * 48;
  float f[8];
  if (q8 < 32) {
    int tok = embed[n];
    const float* src = etab + (size_t)tok * E_ + q8 * 8;
#pragma unroll
    for (int j = 0; j < 8; ++j) f[j] = src[j];
  } else {
    const float* src = c_embed + (size_t)n * CD_ + (q8 - 32) * 8;
#pragma unroll
    for (int j = 0; j < 8; ++j) f[j] = src[j];
  }
  union { uint4 v; unsigned short s[8]; } u;
#pragma unroll
  for (int j = 0; j < 8; ++j) u.s[j] = f2bf(f[j]);
  *(uint4*)(x + (size_t)n * EC_ + q8 * 8) = u.v;
}

// ---------------- fused biLSTM scan: x_proj + recurrence, MFMA ----------------
// 256 wgs = dir(2) x batch-group(4, 16 batch) x unit-group(32, 16 units).
// 4 waves/wg; wave owns 16 gate-rows (4 units x 4 gates, row = u*4+g).
// A (weights) in VGPRs; B (x|h) staged frag-linear in LDS; h exchanged via
// sc0/sc1 relaxed-agent atomics (hx, bf16-pairs); fence-free spin barrier.
__global__ __launch_bounds__(256) void k_scan(
    const unsigned short* __restrict__ x,
    const float* __restrict__ wih_f, const float* __restrict__ whh_f,
    const float* __restrict__ wih_b, const float* __restrict__ whh_b,
    const float* __restrict__ bias_f, const float* __restrict__ bias_b,
    const float* __restrict__ h0, const float* __restrict__ c0,
    unsigned short* __restrict__ Hsc,            // [T][B][1024] bf16
    unsigned* __restrict__ hx,                   // [2ph][2dir][4bg][16b][256jp]
    int* __restrict__ cnt) {
  __shared__ uint4 Bs[1792];                     // 28 ktiles x 64 lanes x 16B
  const int tid  = threadIdx.x;
  const int lane = tid & 63;
  const int w    = tid >> 6;                     // wave 0..3
  const int gid  = blockIdx.x;
  const int dir  = gid >> 7;
  const int bg   = (gid >> 5) & 3;
  const int ug   = gid & 31;
  const int grp  = dir * 4 + bg;

  const float* wih  = dir ? wih_b  : wih_f;      // [2048][384]
  const float* whh  = dir ? whh_b  : whh_f;      // [2048][512]
  const float* bias = dir ? bias_b : bias_f;     // [2048]

  // ---- preload A fragments (bf16) into registers ----
  bf16x8 afrag[28];
  {
    const int m = lane & 15, koct = lane >> 4;   // A-role: row, k-octet
    const int grow = (m & 3) * H_ + ug * 16 + w * 4 + (m >> 2);
#pragma unroll
    for (int kt = 0; kt < 12; ++kt) {
      const float* src = wih + (size_t)grow * EC_ + kt * 32 + koct * 8;
      union { bf16x8 v; unsigned short s[8]; } u;
#pragma unroll
      for (int j = 0; j < 8; ++j) u.s[j] = f2bf(src[j]);
      afrag[kt] = u.v;
    }
#pragma unroll
    for (int kt = 0; kt < 16; ++kt) {
      const float* src = whh + (size_t)grow * H_ + kt * 32 + koct * 8;
      union { bf16x8 v; unsigned short s[8]; } u;
#pragma unroll
      for (int j = 0; j < 8; ++j) u.s[j] = f2bf(src[j]);
      afrag[12 + kt] = u.v;
    }
  }

  // ---- D-role lane identity: (unit, batch); c-state in register ----
  const int bD = bg * 16 + (lane & 15);
  const int jD = ug * 16 + w * 4 + (lane >> 4);
  float bsv[4];
#pragma unroll
  for (int q = 0; q < 4; ++q) bsv[q] = bias[q * H_ + jD];
  float c = c0[(size_t)dir * B_ * H_ + (size_t)bD * H_ + jD];

  const int sb  = tid & 15;                      // staging: batch row
  const int sk8 = tid >> 4;                      // staging: k-octet 0..15

  // producer-side hx slot (bf16 pair), lanes with bit4==0 only
  unsigned* const hxw = hx + (((size_t)dir * 4 + bg) * 16 + (lane & 15)) * 256
                        + ug * 8 + w * 2 + (lane >> 5);
  // consumer-side hx base (per phase added in-loop)
  const unsigned* const hxr = hx + (((size_t)dir * 4 + bg) * 16 + sb) * 256;

  // prefetch x-slice for step 0
  uint4 xv[3];
  {
    const int cur0 = dir ? (T_ - 1) : 0;
    const unsigned short* xsrc = x + (size_t)(cur0 * B_ + bg * 16 + sb) * EC_;
#pragma unroll
    for (int p = 0; p < 3; ++p) xv[p] = *(const uint4*)(xsrc + p * 128 + sk8 * 8);
  }

  for (int s = 0; s < T_; ++s) {
    const int cur = dir ? (T_ - 1 - s) : s;
    __syncthreads();                             // protect Bs from prev readers
    // stage x part (ktiles 0..11) from prefetched regs
#pragma unroll
    for (int p = 0; p < 3; ++p) {
      int k = p * 128 + sk8 * 8;
      Bs[(k >> 5) * 64 + ((k >> 3) & 3) * 16 + sb] = xv[p];
    }
    // stage h part (ktiles 12..27)
    if (s == 0) {
      const float* hsrc = h0 + (size_t)dir * B_ * H_ + (size_t)(bg * 16 + sb) * H_;
#pragma unroll
      for (int p = 0; p < 4; ++p) {
        int kh = p * 128 + sk8 * 8;
        union { uint4 v; unsigned short us[8]; } u;
#pragma unroll
        for (int j = 0; j < 8; ++j) u.us[j] = f2bf(hsrc[kh + j]);
        int k = EC_ + kh;
        Bs[(k >> 5) * 64 + ((k >> 3) & 3) * 16 + sb] = u.v;
      }
    } else {
      const unsigned* hsrc = hxr + (size_t)(((s - 1) & 1) * 2) * 16384;
#pragma unroll
      for (int p = 0; p < 4; ++p) {
        int jp0 = p * 64 + sk8 * 4;
        unsigned u0 = __hip_atomic_load(hsrc + jp0 + 0, __ATOMIC_RELAXED,
                                        __HIP_MEMORY_SCOPE_AGENT);
        unsigned u1 = __hip_atomic_load(hsrc + jp0 + 1, __ATOMIC_RELAXED,
                                        __HIP_MEMORY_SCOPE_AGENT);
        unsigned u2 = __hip_atomic_load(hsrc + jp0 + 2, __ATOMIC_RELAXED,
                                        __HIP_MEMORY_SCOPE_AGENT);
        unsigned u3 = __hip_atomic_load(hsrc + jp0 + 3, __ATOMIC_RELAXED,
                                        __HIP_MEMORY_SCOPE_AGENT);
        int k = EC_ + p * 128 + sk8 * 8;
        Bs[(k >> 5) * 64 + ((k >> 3) & 3) * 16 + sb] =
            make_uint4(u0, u1, u2, u3);
      }
    }
    __syncthreads();

    // prefetch x-slice for next step (hidden under MFMA + barrier)
    if (s + 1 < T_) {
      const int curn = dir ? (T_ - 2 - s) : (s + 1);
      const unsigned short* xsrc = x + (size_t)(curn * B_ + bg * 16 + sb) * EC_;
#pragma unroll
      for (int p = 0; p < 3; ++p) xv[p] = *(const uint4*)(xsrc + p * 128 + sk8 * 8);
    }

    f32x4 acc = {0.f, 0.f, 0.f, 0.f};
#pragma unroll
    for (int kt = 0; kt < 28; ++kt) {
      bf16x8 bfrag = ((const bf16x8*)Bs)[kt * 64 + lane];
      acc = __builtin_amdgcn_mfma_f32_16x16x32_bf16(afrag[kt], bfrag, acc, 0, 0, 0);
    }

    float gi = acc[0] + bsv[0];
    float gf = acc[1] + bsv[1];
    float gg = acc[2] + bsv[2];
    float go = acc[3] + bsv[3];
    float si = 1.f / (1.f + __expf(-gi));
    float sf = 1.f / (1.f + __expf(-gf));
    float so = 1.f / (1.f + __expf(-go));
    c = sf * c + si * tanhf(gg);
    float h = so * tanhf(c);
    unsigned hb = f2bf(h);
    Hsc[(size_t)cur * B_ * 1024 + (size_t)bD * 1024 + dir * H_ + jD] =
        (unsigned short)hb;
    // pack (j even, j odd) bf16 pair and publish to coherence point (sc0 sc1)
    {
      int partner = __shfl_xor((int)hb, 16);
      if (!(lane & 16)) {
        unsigned packed = hb | ((unsigned)partner << 16);
        __hip_atomic_store(hxw + (size_t)((s & 1) * 2) * 16384, packed,
                           __ATOMIC_RELAXED, __HIP_MEMORY_SCOPE_AGENT);
      }
    }

    if (s + 1 < T_) {
      asm volatile("s_waitcnt vmcnt(0)" ::: "memory");  // h stores at coherence pt
      __syncthreads();
      if (tid == 0) {
        int* p = cnt + grp * 16;
        __hip_atomic_fetch_add(p, 1, __ATOMIC_RELAXED, __HIP_MEMORY_SCOPE_AGENT);
        const int target = 32 * (s + 1);         // monotonic counter
        while (__hip_atomic_load(p, __ATOMIC_RELAXED, __HIP_MEMORY_SCOPE_AGENT)
               < target)
          __builtin_amdgcn_s_sleep(2);
      }
      __syncthreads();
    }
  }
}

// ---------------- W_word GEMM fused tanh * w_proj -> logits (fp32) ---------
__global__ __launch_bounds__(256) void k_wword(
    const unsigned short* __restrict__ Hsc, const float* __restrict__ Ww,
    const float* __restrict__ bw, const float* __restrict__ wp,
    float* __restrict__ logits) {
  __shared__ float As[16][132];
  __shared__ float Bsm[16][132];
  __shared__ float scratch[128][17];
  const int tid = threadIdx.x;
  const int db = blockIdx.x, nb = blockIdx.y;
  const int tg = tid >> 4, tn = tid & 15;
  float acc[8][8];
#pragma unroll
  for (int i = 0; i < 8; ++i)
#pragma unroll
    for (int j = 0; j < 8; ++j) acc[i][j] = 0.f;

  for (int k0 = 0; k0 < 1024; k0 += 16) {
    __syncthreads();
    {                                            // A: Hout bf16, 128r x 16k
      int r = tid >> 1, ko = tid & 1;
      union { uint4 v; unsigned short s[8]; } u;
      u.v = *(const uint4*)(Hsc + (size_t)(nb * 128 + r) * 1024 + k0 + ko * 8);
#pragma unroll
      for (int q = 0; q < 8; ++q) As[ko * 8 + q][r] = bf2f(u.s[q]);
    }
    {                                            // B: W_word fp32, 16k x 128c
      int kk = tid >> 4, cc = (tid & 15) * 8;
      const float* src = Ww + (size_t)(k0 + kk) * 1024 + db * 128 + cc;
      *(float4*)&Bsm[kk][cc]     = *(const float4*)(src);
      *(float4*)&Bsm[kk][cc + 4] = *(const float4*)(src + 4);
    }
    __syncthreads();
#pragma unroll 4
    for (int kk = 0; kk < 16; ++kk) {
      float a[8], b[8];
      *(float4*)&a[0] = *(const float4*)&As[kk][tg * 8];
      *(float4*)&a[4] = *(const float4*)&As[kk][tg * 8 + 4];
      *(float4*)&b[0] = *(const float4*)&Bsm[kk][tn * 4];
      *(float4*)&b[4] = *(const float4*)&Bsm[kk][64 + tn * 4];
#pragma unroll
      for (int rr = 0; rr < 8; ++rr)
#pragma unroll
        for (int cc = 0; cc < 8; ++cc)
          acc[rr][cc] = fmaf(a[rr], b[cc], acc[rr][cc]);
    }
  }
  float bwv[8], wpv[8];
#pragma unroll
  for (int cc = 0; cc < 8; ++cc) {
    int dd = db * 128 + ((cc >= 4) ? 64 : 0) + tn * 4 + (cc & 3);
    bwv[cc] = bw[dd]; wpv[cc] = wp[dd];
  }
  float rs[8];
#pragma unroll
  for (int rr = 0; rr < 8; ++rr) {
    float sum = 0.f;
#pragma unroll
    for (int cc = 0; cc < 8; ++cc)
      sum += tanhf(acc[rr][cc] + bwv[cc]) * wpv[cc];
    rs[rr] = sum;
  }
#pragma unroll
  for (int rr = 0; rr < 8; ++rr) scratch[tg * 8 + rr][tn] = rs[rr];
  __syncthreads();
  if (tid < 128) {
    float sum = 0.f;
#pragma unroll
    for (int j = 0; j < 16; ++j) sum += scratch[tid][j];
    atomicAdd(&logits[nb * 128 + tid], sum);
  }
}

// ---------------- softmax over time (per batch column) ----------------
__global__ __launch_bounds__(256) void k_softmax(
    const float* __restrict__ logits, float* __restrict__ attn) {
  __shared__ float red[256];
  const int b = blockIdx.x, tid = threadIdx.x;
  float v0 = logits[(size_t)tid * B_ + b];
  float v1 = logits[(size_t)(tid + 256) * B_ + b];
  red[tid] = fmaxf(v0, v1);
  __syncthreads();
  for (int off = 128; off; off >>= 1) {
    if (tid < off) red[tid] = fmaxf(red[tid], red[tid + off]);
    __syncthreads();
  }
  float m = red[0];
  __syncthreads();
  float e0 = __expf(v0 - m), e1 = __expf(v1 - m);
  red[tid] = e0 + e1;
  __syncthreads();
  for (int off = 128; off; off >>= 1) {
    if (tid < off) red[tid] += red[tid + off];
    __syncthreads();
  }
  float inv = 1.f / red[0];
  attn[(size_t)tid * B_ + b] = e0 * inv;
  attn[(size_t)(tid + 256) * B_ + b] = e1 * inv;
}

// ---------------- ctx[b][d] = sum_t attn[t,b] * Hout[t,b,d] ----------------
__global__ __launch_bounds__(256) void k_ctx(
    const float* __restrict__ attn, const unsigned short* __restrict__ Hsc,
    float* __restrict__ ctx) {
  __shared__ float al[512];
  const int b = blockIdx.x, dc = blockIdx.y, tid = threadIdx.x;
  al[tid]       = attn[(size_t)tid * B_ + b];
  al[tid + 256] = attn[(size_t)(tid + 256) * B_ + b];
  __syncthreads();
  float acc = 0.f;
  const unsigned short* hp = Hsc + (size_t)b * 1024 + dc * 256 + tid;
#pragma unroll 8
  for (int t = 0; t < T_; ++t)
    acc = fmaf(al[t], bf2f(hp[(size_t)t * B_ * 1024]), acc);
  ctx[b * 1024 + dc * 256 + tid] = acc;
}

// ---------------- final linear: out[b][c] ----------------
__global__ __launch_bounds__(64) void k_out(
    const float* __restrict__ ctx, const float* __restrict__ linW,
    const float* __restrict__ linb, float* __restrict__ out) {
  const int b = blockIdx.x, lane = threadIdx.x;
#pragma unroll
  for (int cc = 0; cc < NCLS; ++cc) {
    float p = 0.f;
    for (int d = lane; d < 1024; d += 64)
      p = fmaf(ctx[b * 1024 + d], linW[cc * 1024 + d], p);
    for (int off = 32; off; off >>= 1) p += __shfl_down(p, off);
    if (lane == 0) out[b * NCLS + cc] = p + linb[cc];
  }
}

// ---------------------------------------------------------------------------
extern "C" void kernel_launch(void* const* d_in, const int* in_sizes, int n_in,
                              void* d_out, int out_size, void* d_ws, size_t ws_size,
                              hipStream_t stream) {
  float* out = (float*)d_out;
  if (ws_size < WS_REQ) {
    k_sentinel<<<(out_size + 63) / 64, 64, 0, stream>>>(
        out, out_size, (float)(ws_size >> 20));
    return;
  }
  const int*   embed   = (const int*)d_in[0];
  const float* c_embed = (const float*)d_in[1];
  const float* h0      = (const float*)d_in[2];
  const float* c0      = (const float*)d_in[3];
  const float* etab    = (const float*)d_in[4];
  const float* w_ih_f  = (const float*)d_in[5];
  const float* w_hh_f  = (const float*)d_in[6];
  const float* b_f     = (const float*)d_in[7];
  const float* w_ih_b  = (const float*)d_in[8];
  const float* w_hh_b  = (const float*)d_in[9];
  const float* b_b     = (const float*)d_in[10];
  const float* W_word  = (const float*)d_in[11];
  const float* b_word  = (const float*)d_in[12];
  const float* w_proj  = (const float*)d_in[13];
  const float* lin_W   = (const float*)d_in[14];
  const float* lin_b   = (const float*)d_in[15];

  char* W = (char*)d_ws;
  unsigned short* x    = (unsigned short*)(W + OFF_X);
  unsigned short* Hsc  = (unsigned short*)(W + OFF_HSC);
  float*    logits = (float*)(W + OFF_LOG);
  float*    attn   = (float*)(W + OFF_ATTN);
  float*    ctx    = (float*)(W + OFF_CTX);
  int*      cnt    = (int*)(W + OFF_CNT);
  unsigned* hx     = (unsigned*)(W + OFF_HX);

  // zero logits (atomic target) + barrier counters each launch (replay-safe)
  hipMemsetAsync(logits, 0, 528384, stream);

  k_gather <<<6144, 256, 0, stream>>>(embed, c_embed, etab, x);
  k_scan   <<<256, 256, 0, stream>>>(x, w_ih_f, w_hh_f, w_ih_b, w_hh_b,
                                     b_f, b_b, h0, c0, Hsc, hx, cnt);
  k_wword  <<<dim3(8, 256), 256, 0, stream>>>(Hsc, W_word, b_word, w_proj, logits);
  k_softmax<<<64, 256, 0, stream>>>(logits, attn);
  k_ctx    <<<dim3(64, 4), 256, 0, stream>>>(attn, Hsc, ctx);
  k_out    <<<64, 64, 0, stream>>>(ctx, lin_W, lin_b, out);
}

// Round 5
// 2945.081 us; speedup vs baseline: 7.9084x; 1.3258x over previous
//
#include <hip/hip_runtime.h>
#include <cstdint>
#include <cstddef>

// ---------------------------------------------------------------------------
// AttentionWordRNN on MI355X — ROUND 5.
// k_scan: 512-thr wgs (16/group), flag-array barrier (no atomics-RMW), h sc-
//   loads issued before x-part MFMAs (latency hidden), 2-way MFMA acc chains.
// k_wword: bf16 MFMA GEMM on pre-transposed W_word (k_cvtw), register-only.
// Exchange semantics identical to proven round-4 (relaxed agent sc ops).
// ---------------------------------------------------------------------------

#define T_    512
#define B_    64
#define E_    256
#define CD_   128
#define EC_   384      // E + CDIM
#define H_    512
#define NCLS  5
#define NTOK  32768    // T*B

// byte offsets into d_ws
#define OFF_X      0UL
#define OFF_HSC    25165824UL
#define OFF_LOG    92274688UL
#define OFF_ATTN   92405760UL
#define OFF_CTX    92536832UL
#define OFF_FLAGS  92798976UL
#define OFF_HX     92801024UL
#define OFF_WWT    93063168UL
#define WS_REQ     95160320UL

typedef __attribute__((ext_vector_type(8))) short bf16x8;
typedef __attribute__((ext_vector_type(4))) float f32x4;

__device__ __forceinline__ unsigned short f2bf(float f) {
  union { float f; unsigned u; } v; v.f = f;
  unsigned r = v.u + 0x7FFFu + ((v.u >> 16) & 1u);   // RNE
  return (unsigned short)(r >> 16);
}
__device__ __forceinline__ float bf2f(unsigned short h) {
  union { unsigned u; float f; } v; v.u = ((unsigned)h) << 16;
  return v.f;
}

// ---------------- ws-too-small sentinel ----------------
__global__ void k_sentinel(float* __restrict__ out, int n, float val) {
  int i = blockIdx.x * 64 + threadIdx.x;
  if (i < n) out[i] = val;
}

// ---------------- gather + concat -> x bf16 [NTOK][384] ----------------
__global__ __launch_bounds__(256) void k_gather(
    const int* __restrict__ embed, const float* __restrict__ c_embed,
    const float* __restrict__ etab, unsigned short* __restrict__ x) {
  int idx = blockIdx.x * 256 + threadIdx.x;     // NTOK*48 exact
  int n = idx / 48;
  int q8 = idx - n * 48;
  float f[8];
  if (q8 < 32) {
    int tok = embed[n];
    const float* src = etab + (size_t)tok * E_ + q8 * 8;
#pragma unroll
    for (int j = 0; j < 8; ++j) f[j] = src[j];
  } else {
    const float* src = c_embed + (size_t)n * CD_ + (q8 - 32) * 8;
#pragma unroll
    for (int j = 0; j < 8; ++j) f[j] = src[j];
  }
  union { uint4 v; unsigned short s[8]; } u;
#pragma unroll
  for (int j = 0; j < 8; ++j) u.s[j] = f2bf(f[j]);
  *(uint4*)(x + (size_t)n * EC_ + q8 * 8) = u.v;
}

// ---------------- W_word fp32 [k][d] -> bf16 transposed wwT [d][k] ---------
__global__ __launch_bounds__(256) void k_cvtw(
    const float* __restrict__ Ww, unsigned short* __restrict__ wwT) {
  __shared__ float t[64][65];
  const int kb = blockIdx.x >> 4, db = blockIdx.x & 15;
  const int r = threadIdx.x >> 4, c4 = (threadIdx.x & 15) * 4;
#pragma unroll
  for (int p = 0; p < 4; ++p) {
    float4 v = *(const float4*)(Ww + (size_t)(kb * 64 + p * 16 + r) * 1024
                                + db * 64 + c4);
    t[p * 16 + r][c4 + 0] = v.x; t[p * 16 + r][c4 + 1] = v.y;
    t[p * 16 + r][c4 + 2] = v.z; t[p * 16 + r][c4 + 3] = v.w;
  }
  __syncthreads();
#pragma unroll
  for (int p = 0; p < 4; ++p) {
    union { ushort4 v; unsigned short s[4]; } o;
#pragma unroll
    for (int j = 0; j < 4; ++j) o.s[j] = f2bf(t[c4 + j][p * 16 + r]);
    *(ushort4*)(wwT + (size_t)(db * 64 + p * 16 + r) * 1024 + kb * 64 + c4) = o.v;
  }
}

// ---------------- fused biLSTM scan: x_proj + recurrence, MFMA ----------------
// 128 wgs of 512 thr = dir(2) x bg(4) x ug(16, 32 units); grp = gid&7 so group
// members share an XCD under round-robin dispatch (perf-only heuristic).
// Flag-array barrier: 16 dwords/group in one 64B line, all-lane poll.
__global__ __launch_bounds__(512) void k_scan(
    const unsigned short* __restrict__ x,
    const float* __restrict__ wih_f, const float* __restrict__ whh_f,
    const float* __restrict__ wih_b, const float* __restrict__ whh_b,
    const float* __restrict__ bias_f, const float* __restrict__ bias_b,
    const float* __restrict__ h0, const float* __restrict__ c0,
    unsigned short* __restrict__ Hsc,            // [T][B][1024] bf16
    unsigned* __restrict__ hx,                   // [2par][8grp][16b][256jp] dwords
    int* __restrict__ flags) {                   // [8grp][64] dwords (16 used)
  __shared__ uint4 Bs[1792];                     // 28 ktiles x 64 lanes x 16B
  uint2* const Bs2 = (uint2*)Bs;
  const int tid  = threadIdx.x;
  const int lane = tid & 63;
  const int w    = tid >> 6;                     // wave 0..7
  const int gid  = blockIdx.x;
  const int grp  = gid & 7;                      // dir*4+bg
  const int ug   = gid >> 3;                     // 0..15
  const int dir  = grp >> 2;
  const int bg   = grp & 3;

  const float* wih  = dir ? wih_b  : wih_f;      // [2048][384]
  const float* whh  = dir ? whh_b  : whh_f;      // [2048][512]
  const float* bias = dir ? bias_b : bias_f;     // [2048]

  // ---- preload A fragments (bf16) into registers ----
  bf16x8 afrag[28];
  {
    const int m = lane & 15, koct = lane >> 4;   // A-role: row, k-octet
    const int grow = (m & 3) * H_ + ug * 32 + w * 4 + (m >> 2);
#pragma unroll
    for (int kt = 0; kt < 12; ++kt) {
      const float* src = wih + (size_t)grow * EC_ + kt * 32 + koct * 8;
      union { bf16x8 v; unsigned short s[8]; } u;
#pragma unroll
      for (int j = 0; j < 8; ++j) u.s[j] = f2bf(src[j]);
      afrag[kt] = u.v;
    }
#pragma unroll
    for (int kt = 0; kt < 16; ++kt) {
      const float* src = whh + (size_t)grow * H_ + kt * 32 + koct * 8;
      union { bf16x8 v; unsigned short s[8]; } u;
#pragma unroll
      for (int j = 0; j < 8; ++j) u.s[j] = f2bf(src[j]);
      afrag[12 + kt] = u.v;
    }
  }

  // ---- D-role lane identity: (unit, batch); c-state in register ----
  const int bD = bg * 16 + (lane & 15);
  const int jD = ug * 32 + w * 4 + (lane >> 4);
  float bsv[4];
#pragma unroll
  for (int q = 0; q < 4; ++q) bsv[q] = bias[q * H_ + jD];
  float c = c0[(size_t)dir * B_ * H_ + (size_t)bD * H_ + jD];

  const int sb = tid & 15;                       // staging: batch row
  const int sk = tid >> 4;                       // staging: 0..31

  // producer-side hx dword slot (bf16 pair), lanes with bit4==0 only
  const int jpw = ug * 16 + w * 2 + (lane >> 5);
  unsigned* const hxw = hx + ((size_t)grp * 16 + (lane & 15)) * 256 + jpw;
  // consumer-side base (parity added in-loop); parity stride = 8*16*256
  const unsigned* const hxr = hx + ((size_t)grp * 16 + sb) * 256;
  int* const fp = flags + grp * 64 + (lane & 15);

  // prefetch x-slice for step 0 (3 x uint2 per thread)
  uint2 xv[3];
  {
    const int cur0 = dir ? (T_ - 1) : 0;
    const unsigned short* xsrc = x + (size_t)(cur0 * B_ + bg * 16 + sb) * EC_;
#pragma unroll
    for (int p = 0; p < 3; ++p)
      xv[p] = *(const uint2*)(xsrc + (p * 32 + sk) * 4);
  }

  for (int s = 0; s < T_; ++s) {
    const int cur = dir ? (T_ - 1 - s) : s;
    __syncthreads();                             // all waves done with prev Bs
    // stage x part (ktiles 0..11): k = q*4, q = p*32+sk
#pragma unroll
    for (int p = 0; p < 3; ++p) {
      int q = p * 32 + sk;
      Bs2[(q >> 3) * 128 + ((q >> 1) & 3) * 32 + sb * 2 + (q & 1)] = xv[p];
    }
    __syncthreads();                             // Bs.x ready

    // poll: h for this step published by all 16 wgs of the group
    if (s) {
      while (true) {
        int f = __hip_atomic_load(fp, __ATOMIC_RELAXED, __HIP_MEMORY_SCOPE_AGENT);
        if (__all(f >= s)) break;
        __builtin_amdgcn_s_sleep(1);
      }
    }

    // issue h loads (latency hidden under x-part MFMAs below)
    uint2 hv[4];
    if (s == 0) {
      const float* hsrc = h0 + (size_t)dir * B_ * H_ + (size_t)(bg * 16 + sb) * H_;
#pragma unroll
      for (int p = 0; p < 4; ++p) {
        int u0 = (p * 32 + sk) * 4;
        hv[p].x = (unsigned)f2bf(hsrc[u0 + 0]) | ((unsigned)f2bf(hsrc[u0 + 1]) << 16);
        hv[p].y = (unsigned)f2bf(hsrc[u0 + 2]) | ((unsigned)f2bf(hsrc[u0 + 3]) << 16);
      }
    } else {
      const unsigned* hsrc = hxr + (size_t)(((s - 1) & 1) * 8 * 16) * 256;
#pragma unroll
      for (int p = 0; p < 4; ++p) {
        int jp0 = (p * 32 + sk) * 2;
        hv[p].x = __hip_atomic_load(hsrc + jp0 + 0, __ATOMIC_RELAXED,
                                    __HIP_MEMORY_SCOPE_AGENT);
        hv[p].y = __hip_atomic_load(hsrc + jp0 + 1, __ATOMIC_RELAXED,
                                    __HIP_MEMORY_SCOPE_AGENT);
      }
    }

    // x-part MFMAs (ktiles 0..11), two independent chains
    f32x4 aA = {0.f, 0.f, 0.f, 0.f}, aB = {0.f, 0.f, 0.f, 0.f};
#pragma unroll
    for (int kt = 0; kt < 12; kt += 2) {
      bf16x8 b0 = ((const bf16x8*)Bs)[kt * 64 + lane];
      bf16x8 b1 = ((const bf16x8*)Bs)[(kt + 1) * 64 + lane];
      aA = __builtin_amdgcn_mfma_f32_16x16x32_bf16(afrag[kt], b0, aA, 0, 0, 0);
      aB = __builtin_amdgcn_mfma_f32_16x16x32_bf16(afrag[kt + 1], b1, aB, 0, 0, 0);
    }

    // stage h part (ktiles 12..27): q = 96 + p*32 + sk
#pragma unroll
    for (int p = 0; p < 4; ++p) {
      int q = 96 + p * 32 + sk;
      Bs2[(q >> 3) * 128 + ((q >> 1) & 3) * 32 + sb * 2 + (q & 1)] = hv[p];
    }
    __syncthreads();                             // Bs.h ready

    // h-part MFMAs (ktiles 12..27)
#pragma unroll
    for (int kt = 12; kt < 28; kt += 2) {
      bf16x8 b0 = ((const bf16x8*)Bs)[kt * 64 + lane];
      bf16x8 b1 = ((const bf16x8*)Bs)[(kt + 1) * 64 + lane];
      aA = __builtin_amdgcn_mfma_f32_16x16x32_bf16(afrag[kt], b0, aA, 0, 0, 0);
      aB = __builtin_amdgcn_mfma_f32_16x16x32_bf16(afrag[kt + 1], b1, aB, 0, 0, 0);
    }

    float gi = aA[0] + aB[0] + bsv[0];
    float gf = aA[1] + aB[1] + bsv[1];
    float gg = aA[2] + aB[2] + bsv[2];
    float go = aA[3] + aB[3] + bsv[3];
    float si = 1.f / (1.f + __expf(-gi));
    float sf = 1.f / (1.f + __expf(-gf));
    float so = 1.f / (1.f + __expf(-go));
    c = sf * c + si * tanhf(gg);
    float h = so * tanhf(c);
    unsigned hb = f2bf(h);
    Hsc[(size_t)cur * B_ * 1024 + (size_t)bD * 1024 + dir * H_ + jD] =
        (unsigned short)hb;
    {
      int partner = __shfl_xor((int)hb, 16);
      if (!(lane & 16)) {
        unsigned packed = hb | ((unsigned)partner << 16);
        __hip_atomic_store(hxw + (size_t)((s & 1) * 8 * 16) * 256, packed,
                           __ATOMIC_RELAXED, __HIP_MEMORY_SCOPE_AGENT);
      }
    }

    if (s + 1 < T_) {
      asm volatile("s_waitcnt vmcnt(0)" ::: "memory"); // my wave's h at IF$
      __syncthreads();                                 // all waves drained
      if (tid == 0)
        __hip_atomic_store(flags + grp * 64 + ug, s + 1,
                           __ATOMIC_RELAXED, __HIP_MEMORY_SCOPE_AGENT);
      // prefetch next x-slice (completion awaited at next Bs.x write)
      const int curn = dir ? (T_ - 2 - s) : (s + 1);
      const unsigned short* xsrc = x + (size_t)(curn * B_ + bg * 16 + sb) * EC_;
#pragma unroll
      for (int p = 0; p < 3; ++p)
        xv[p] = *(const uint2*)(xsrc + (p * 32 + sk) * 4);
    }
  }
}

// ---------------- W_word bf16 MFMA fused tanh * w_proj -> logits -----------
// block = 4 waves, computes [64 tok] x [128 d], K = 1024; no LDS mainloop.
__global__ __launch_bounds__(256) void k_wword(
    const unsigned short* __restrict__ Hsc, const unsigned short* __restrict__ wwT,
    const float* __restrict__ bw, const float* __restrict__ wp,
    float* __restrict__ logits) {
  const int lane = threadIdx.x & 63;
  const int wv   = threadIdx.x >> 6;             // 0..3
  const int db = blockIdx.x;                     // 0..7
  const int nb = blockIdx.y;                     // 0..511
  const int tokbase = nb * 64 + wv * 16;
  const int m = lane & 15, koct = lane >> 4;
  const unsigned short* aptr = Hsc + (size_t)(tokbase + m) * 1024 + koct * 8;
  const unsigned short* bptr = wwT + (size_t)(db * 128 + m) * 1024 + koct * 8;

  f32x4 acc[8];
#pragma unroll
  for (int dt = 0; dt < 8; ++dt) acc[dt] = (f32x4){0.f, 0.f, 0.f, 0.f};

  for (int k0 = 0; k0 < 1024; k0 += 32) {
    bf16x8 af = *(const bf16x8*)(aptr + k0);
#pragma unroll
    for (int dt = 0; dt < 8; ++dt) {
      bf16x8 bf = *(const bf16x8*)(bptr + (size_t)dt * 16 * 1024 + k0);
      acc[dt] = __builtin_amdgcn_mfma_f32_16x16x32_bf16(af, bf, acc[dt], 0, 0, 0);
    }
  }
  // lane holds: tok = tokbase + (lane>>4)*4 + q, d = db*128 + dt*16 + (lane&15)
  float rs[4] = {0.f, 0.f, 0.f, 0.f};
  const int d0 = db * 128 + (lane & 15);
#pragma unroll
  for (int dt = 0; dt < 8; ++dt) {
    float bwv = bw[d0 + dt * 16], wpv = wp[d0 + dt * 16];
#pragma unroll
    for (int q = 0; q < 4; ++q)
      rs[q] += tanhf(acc[dt][q] + bwv) * wpv;
  }
#pragma unroll
  for (int off = 1; off < 16; off <<= 1)
#pragma unroll
    for (int q = 0; q < 4; ++q) rs[q] += __shfl_xor(rs[q], off);
  if ((lane & 15) == 0) {
    const int tok = tokbase + (lane >> 4) * 4;
#pragma unroll
    for (int q = 0; q < 4; ++q) atomicAdd(&logits[tok + q], rs[q]);
  }
}

// ---------------- softmax over time (per batch column) ----------------
__global__ __launch_bounds__(256) void k_softmax(
    const float* __restrict__ logits, float* __restrict__ attn) {
  __shared__ float red[256];
  const int b = blockIdx.x, tid = threadIdx.x;
  float v0 = logits[(size_t)tid * B_ + b];
  float v1 = logits[(size_t)(tid + 256) * B_ + b];
  red[tid] = fmaxf(v0, v1);
  __syncthreads();
  for (int off = 128; off; off >>= 1) {
    if (tid < off) red[tid] = fmaxf(red[tid], red[tid + off]);
    __syncthreads();
  }
  float m = red[0];
  __syncthreads();
  float e0 = __expf(v0 - m), e1 = __expf(v1 - m);
  red[tid] = e0 + e1;
  __syncthreads();
  for (int off = 128; off; off >>= 1) {
    if (tid < off) red[tid] += red[tid + off];
    __syncthreads();
  }
  float inv = 1.f / red[0];
  attn[(size_t)tid * B_ + b] = e0 * inv;
  attn[(size_t)(tid + 256) * B_ + b] = e1 * inv;
}

// ---------------- ctx[b][d] = sum_t attn[t,b] * Hout[t,b,d] ----------------
__global__ __launch_bounds__(256) void k_ctx(
    const float* __restrict__ attn, const unsigned short* __restrict__ Hsc,
    float* __restrict__ ctx) {
  __shared__ float al[512];
  const int b = blockIdx.x, dc = blockIdx.y, tid = threadIdx.x;
  al[tid]       = attn[(size_t)tid * B_ + b];
  al[tid + 256] = attn[(size_t)(tid + 256) * B_ + b];
  __syncthreads();
  float acc = 0.f;
  const unsigned short* hp = Hsc + (size_t)b * 1024 + dc * 256 + tid;
#pragma unroll 8
  for (int t = 0; t < T_; ++t)
    acc = fmaf(al[t], bf2f(hp[(size_t)t * B_ * 1024]), acc);
  ctx[b * 1024 + dc * 256 + tid] = acc;
}

// ---------------- final linear: out[b][c] ----------------
__global__ __launch_bounds__(64) void k_out(
    const float* __restrict__ ctx, const float* __restrict__ linW,
    const float* __restrict__ linb, float* __restrict__ out) {
  const int b = blockIdx.x, lane = threadIdx.x;
#pragma unroll
  for (int cc = 0; cc < NCLS; ++cc) {
    float p = 0.f;
    for (int d = lane; d < 1024; d += 64)
      p = fmaf(ctx[b * 1024 + d], linW[cc * 1024 + d], p);
    for (int off = 32; off; off >>= 1) p += __shfl_down(p, off);
    if (lane == 0) out[b * NCLS + cc] = p + linb[cc];
  }
}

// ---------------------------------------------------------------------------
extern "C" void kernel_launch(void* const* d_in, const int* in_sizes, int n_in,
                              void* d_out, int out_size, void* d_ws, size_t ws_size,
                              hipStream_t stream) {
  float* out = (float*)d_out;
  if (ws_size < WS_REQ) {
    k_sentinel<<<(out_size + 63) / 64, 64, 0, stream>>>(
        out, out_size, (float)(ws_size >> 20));
    return;
  }
  const int*   embed   = (const int*)d_in[0];
  const float* c_embed = (const float*)d_in[1];
  const float* h0      = (const float*)d_in[2];
  const float* c0      = (const float*)d_in[3];
  const float* etab    = (const float*)d_in[4];
  const float* w_ih_f  = (const float*)d_in[5];
  const float* w_hh_f  = (const float*)d_in[6];
  const float* b_f     = (const float*)d_in[7];
  const float* w_ih_b  = (const float*)d_in[8];
  const float* w_hh_b  = (const float*)d_in[9];
  const float* b_b     = (const float*)d_in[10];
  const float* W_word  = (const float*)d_in[11];
  const float* b_word  = (const float*)d_in[12];
  const float* w_proj  = (const float*)d_in[13];
  const float* lin_W   = (const float*)d_in[14];
  const float* lin_b   = (const float*)d_in[15];

  char* W = (char*)d_ws;
  unsigned short* x    = (unsigned short*)(W + OFF_X);
  unsigned short* Hsc  = (unsigned short*)(W + OFF_HSC);
  float*          logits = (float*)(W + OFF_LOG);
  float*          attn   = (float*)(W + OFF_ATTN);
  float*          ctx    = (float*)(W + OFF_CTX);
  int*            flags  = (int*)(W + OFF_FLAGS);
  unsigned*       hx     = (unsigned*)(W + OFF_HX);
  unsigned short* wwT    = (unsigned short*)(W + OFF_WWT);

  // zero logits (atomic target) + flags each launch (graph-replay-safe)
  hipMemsetAsync(logits, 0, NTOK * sizeof(float), stream);
  hipMemsetAsync(flags, 0, 2048, stream);

  k_gather <<<6144, 256, 0, stream>>>(embed, c_embed, etab, x);
  k_cvtw   <<<256, 256, 0, stream>>>(W_word, wwT);
  k_scan   <<<128, 512, 0, stream>>>(x, w_ih_f, w_hh_f, w_ih_b, w_hh_b,
                                     b_f, b_b, h0, c0, Hsc, hx, flags);
  k_wword  <<<dim3(8, 512), 256, 0, stream>>>(Hsc, wwT, b_word, w_proj, logits);
  k_softmax<<<64, 256, 0, stream>>>(logits, attn);
  k_ctx    <<<dim3(64, 4), 256, 0, stream>>>(attn, Hsc, ctx);
  k_out    <<<64, 64, 0, stream>>>(ctx, lin_W, lin_b, out);
}